// Round 2
// baseline (11475.587 us; speedup 1.0000x reference)
//
#include <hip/hip_runtime.h>
#include <hip/hip_bf16.h>

// NeuralODE Bosh3 fixed-step integrator, persistent-block formulation.
// B=2048 batch rows, 128 blocks x 16 rows; each block runs all 127 steps.
// Weights pre-packed to bf16 MFMA B-fragment layout in d_ws (L2-resident).

#define B_ 2048
#define L_ 128
#define P_ 8
#define W_ 512
#define T_ 128

typedef __attribute__((ext_vector_type(8))) short short8;
typedef __attribute__((ext_vector_type(4))) float f32x4;

// packed weight sizes (ushort elements)
#define W0P_ELEMS (32*5*64*8)    // N=512 (32 nt), Kpad=160 (5 kt)
#define W1P_ELEMS (32*16*64*8)   // N=512, K=512 (16 kt)
#define W2P_ELEMS (8*16*64*8)    // N=128 (8 nt), K=512
#define W1P_OFF (W0P_ELEMS)
#define W2P_OFF (W0P_ELEMS + W1P_ELEMS)
#define WTOT (W0P_ELEMS + W1P_ELEMS + W2P_ELEMS)   // 409600 ushorts = 819200 B

__device__ __forceinline__ unsigned short f2bf(float f){
  unsigned u = __builtin_bit_cast(unsigned, f);
  u += 0x7fffu + ((u >> 16) & 1u);          // round-to-nearest-even
  return (unsigned short)(u >> 16);
}

__device__ __forceinline__ float tanh_fast(float x){
  float e = __expf(2.0f * x);
  return 1.0f - __fdividef(2.0f, e + 1.0f); // exact at saturation (+-1)
}

// Pack W[n][k] (row-major fp32, fan_out x fan_in) into MFMA B-fragments:
// dst[((nt*KT + kt)*64 + lane)*8 + j] = bf16(W[nt*16+(lane&15)][kt*32+(lane>>4)*8+j])
// Also: idx in [WTOT, WTOT+T_-1) computes dts[idx-WTOT] = ts[i+1]-ts[i] (fp32)
// stored at wp + WTOT (as float*).
__global__ void prep_weights(const float* __restrict__ W0,
                             const float* __restrict__ W1,
                             const float* __restrict__ W2,
                             const float* __restrict__ ts,
                             unsigned short* __restrict__ wp){
  int idx = blockIdx.x * blockDim.x + threadIdx.x;
  if (idx >= WTOT){
    int t = idx - WTOT;
    if (t < T_ - 1){
      float* dts = (float*)(wp + WTOT);
      dts[t] = ts[t+1] - ts[t];           // per-thread VGPR math: no constant-bus issue
    }
    return;
  }
  const float* src; int base, KT, Korig;
  if (idx < W1P_OFF)      { src = W0; base = 0;       KT = 5;  Korig = 136; }
  else if (idx < W2P_OFF) { src = W1; base = W1P_OFF; KT = 16; Korig = 512; }
  else                    { src = W2; base = W2P_OFF; KT = 16; Korig = 512; }
  int e    = idx - base;
  int j    = e & 7;
  int frag = e >> 3;
  int lane = frag & 63;
  int tile = frag >> 6;
  int kt   = tile % KT;
  int nt   = tile / KT;
  int row  = nt*16 + (lane & 15);
  int k    = kt*32 + ((lane >> 4) << 3) + j;
  float v  = (k < Korig) ? src[row*Korig + k] : 0.0f;
  wp[idx] = f2bf(v);
}

// LDS activation layouts (bf16, XOR-swizzled: byte ^= (row&7)<<4; strides are
// multiples of 128B so the swizzle stays within the row -> bijective).
#define XROWB 384    // x buffer: 192 ushorts/row (cols 0..127 y, 128..135 args, rest 0)
#define HROWB 1024   // h buffers: 512 ushorts/row

__global__ __launch_bounds__(512, 2)
void ode_main(const float* __restrict__ x0,
              const float* __restrict__ args,
              const float* __restrict__ b0, const float* __restrict__ b1,
              const float* __restrict__ b2,
              const unsigned short* __restrict__ wp,
              float* __restrict__ out){
  __shared__ __align__(16) unsigned short xb[16*(XROWB/2)];
  __shared__ __align__(16) unsigned short h1[16*(HROWB/2)];
  __shared__ __align__(16) unsigned short h2[16*(HROWB/2)];

  const int tid  = threadIdx.x;
  const int lane = tid & 63;
  const int w    = tid >> 6;     // wave 0..7
  const int lo   = lane & 15;
  const int hi   = lane >> 4;    // 0..3
  const int r0   = blockIdx.x * 16;

  const unsigned short* w0p = wp;
  const unsigned short* w1p = wp + W1P_OFF;
  const unsigned short* w2p = wp + W2P_OFF;
  const float* dts = (const float*)(wp + WTOT);

  // zero x buffer (zeroes are swizzle-invariant)
  for (int i = tid; i < 16*(XROWB/2); i += 512) xb[i] = 0;
  __syncthreads();

  // args -> x cols 128..135 (constant across all steps)
  if (tid < 128){
    int r = tid >> 3, p = tid & 7;
    unsigned short v = f2bf(args[(r0 + r)*P_ + p]);
    *(unsigned short*)((char*)xb + r*XROWB + (((128 + p)*2) ^ ((r & 7) << 4))) = v;
  }

  // per-thread persistent ODE state: rows 4*hi+j, col c3 = w*16+lo (j=0..3)
  const int c3 = w*16 + lo;
  float yr[4], yn[4];
  float b2v = b2[c3];
  float b0v[4], b1v[4];
  #pragma unroll
  for (int i = 0; i < 4; ++i){
    b0v[i] = b0[(w + 8*i)*16 + lo];
    b1v[i] = b1[(w + 8*i)*16 + lo];
  }
  #pragma unroll
  for (int j = 0; j < 4; ++j){
    int row = 4*hi + j;
    float v = x0[(r0 + row)*L_ + c3];
    yr[j] = v;
    out[((r0 + row)*T_ + 0)*L_ + c3] = v;               // ys[:,0,:] = x0
    *(unsigned short*)((char*)xb + row*XROWB + ((c3*2) ^ ((row & 7) << 4))) = f2bf(v);
  }

  // One vector-field eval: x(LDS) -> h1 -> h2 -> d (layer-3 accum, no bias yet)
  auto evalf = [&](f32x4& dout){
    // layer 1: K=160 (5 kt), N=512; wave w owns nt = w+8i
    #pragma unroll
    for (int i = 0; i < 4; ++i){
      int nt = w + 8*i;
      f32x4 acc = {0.f,0.f,0.f,0.f};
      #pragma unroll
      for (int kt = 0; kt < 5; ++kt){
        short8 a = *(const short8*)((const char*)xb + lo*XROWB + ((kt*64 + hi*16) ^ ((lo & 7) << 4)));
        short8 b = *(const short8*)(w0p + ((nt*5 + kt)*64 + lane)*8);
        acc = __builtin_amdgcn_mfma_f32_16x16x32_bf16(a, b, acc, 0, 0, 0);
      }
      #pragma unroll
      for (int j = 0; j < 4; ++j){
        float v = tanh_fast(acc[j] + b0v[i]);
        int row = 4*hi + j;
        *(unsigned short*)((char*)h1 + row*HROWB + (((nt*16 + lo)*2) ^ ((row & 7) << 4))) = f2bf(v);
      }
    }
    __syncthreads();
    // layer 2: K=512 (16 kt), N=512
    #pragma unroll
    for (int i = 0; i < 4; ++i){
      int nt = w + 8*i;
      f32x4 acc = {0.f,0.f,0.f,0.f};
      #pragma unroll
      for (int kt = 0; kt < 16; ++kt){
        short8 a = *(const short8*)((const char*)h1 + lo*HROWB + ((kt*64 + hi*16) ^ ((lo & 7) << 4)));
        short8 b = *(const short8*)(w1p + ((nt*16 + kt)*64 + lane)*8);
        acc = __builtin_amdgcn_mfma_f32_16x16x32_bf16(a, b, acc, 0, 0, 0);
      }
      #pragma unroll
      for (int j = 0; j < 4; ++j){
        float v = tanh_fast(acc[j] + b1v[i]);
        int row = 4*hi + j;
        *(unsigned short*)((char*)h2 + row*HROWB + (((nt*16 + lo)*2) ^ ((row & 7) << 4))) = f2bf(v);
      }
    }
    __syncthreads();
    // layer 3: K=512 (16 kt), N=128; wave w owns nt = w
    f32x4 acc = {0.f,0.f,0.f,0.f};
    #pragma unroll
    for (int kt = 0; kt < 16; ++kt){
      short8 a = *(const short8*)((const char*)h2 + lo*HROWB + ((kt*64 + hi*16) ^ ((lo & 7) << 4)));
      short8 b = *(const short8*)(w2p + ((w*16 + kt)*64 + lane)*8);
      acc = __builtin_amdgcn_mfma_f32_16x16x32_bf16(a, b, acc, 0, 0, 0);
    }
    dout = acc;
  };

  // Bosh3: k1=f(y); k2=f(y+dt/2 k1); k3=f(y+3dt/4 k2); y+=dt(2/9 k1+1/3 k2+4/9 k3)
  for (int t = 1; t < T_; ++t){
    float dt = dts[t-1];
    f32x4 d;

    __syncthreads();                       // xb ready
    evalf(d);                              // k1
    #pragma unroll
    for (int j = 0; j < 4; ++j){
      float k = d[j] + b2v;
      yn[j] = yr[j] + dt*(2.0f/9.0f)*k;
      float xs = yr[j] + 0.5f*dt*k;
      int row = 4*hi + j;
      *(unsigned short*)((char*)xb + row*XROWB + ((c3*2) ^ ((row & 7) << 4))) = f2bf(xs);
    }

    __syncthreads();
    evalf(d);                              // k2
    #pragma unroll
    for (int j = 0; j < 4; ++j){
      float k = d[j] + b2v;
      yn[j] += dt*(1.0f/3.0f)*k;
      float xs = yr[j] + 0.75f*dt*k;
      int row = 4*hi + j;
      *(unsigned short*)((char*)xb + row*XROWB + ((c3*2) ^ ((row & 7) << 4))) = f2bf(xs);
    }

    __syncthreads();
    evalf(d);                              // k3
    #pragma unroll
    for (int j = 0; j < 4; ++j){
      float k = d[j] + b2v;
      yn[j] += dt*(4.0f/9.0f)*k;
      yr[j] = yn[j];
      int row = 4*hi + j;
      out[((r0 + row)*T_ + t)*L_ + c3] = yr[j];
      *(unsigned short*)((char*)xb + row*XROWB + ((c3*2) ^ ((row & 7) << 4))) = f2bf(yr[j]);
    }
  }
}

extern "C" void kernel_launch(void* const* d_in, const int* in_sizes, int n_in,
                              void* d_out, int out_size, void* d_ws, size_t ws_size,
                              hipStream_t stream) {
  const float* x0   = (const float*)d_in[0];
  const float* ts   = (const float*)d_in[1];
  const float* args = (const float*)d_in[2];
  const float* W0   = (const float*)d_in[3];
  const float* b0   = (const float*)d_in[4];
  const float* W1   = (const float*)d_in[5];
  const float* b1   = (const float*)d_in[6];
  const float* W2   = (const float*)d_in[7];
  const float* b2   = (const float*)d_in[8];
  unsigned short* wp = (unsigned short*)d_ws;   // 819,200 B weights + 512 B dts
  float* out = (float*)d_out;

  prep_weights<<<(WTOT + T_ + 255)/256, 256, 0, stream>>>(W0, W1, W2, ts, wp);
  ode_main<<<128, 512, 0, stream>>>(x0, args, b0, b1, b2, wp, out);
}